// Round 5
// baseline (348.038 us; speedup 1.0000x reference)
//
#include <hip/hip_runtime.h>

#define D 128
#define BN_EPS 1e-5f
#define NBUCK 512     // coarse buckets, dst>>8 (391 used at N=100K), 256 nodes/bucket
#define BSHIFT 8
#define BNODES 256    // nodes per bucket

using short8 = __attribute__((ext_vector_type(8))) short;
using floatx4 = __attribute__((ext_vector_type(4))) float;

__device__ inline unsigned short f2bf(float f) {
    unsigned u = __float_as_uint(f);
    u += 0x7fff + ((u >> 16) & 1);  // RNE
    return (unsigned short)(u >> 16);
}
__device__ inline float bf2f(unsigned short s) {
    return __uint_as_float(((unsigned)s) << 16);
}

// ---------- wt: fallback-path only (fast path fuses this into pAwt) ----------
__global__ void wt_kernel(const float* __restrict__ W, const float* __restrict__ b,
                          const float* __restrict__ gamma, const float* __restrict__ beta,
                          const float* __restrict__ mean, const float* __restrict__ var,
                          unsigned short* __restrict__ Wt, float* __restrict__ scv,
                          float* __restrict__ pov) {
    int t = blockIdx.x * blockDim.x + threadIdx.x;
    int k = t >> 7, n = t & 127;
    Wt[(size_t)n * D + k] = f2bf(W[t]);
    if (t < D) {
        float sc = gamma[t] * rsqrtf(var[t] + BN_EPS);
        scv[t] = sc;
        pov[t] = (b[t] - mean[t]) * sc + beta[t];
    }
}

// ---------- pAwt: bucket histogram + Wt transpose/BN affine + xs=bf16(x) ----
// xs carries NO dinv (applied at gather time; dinv is L2-resident 400KB).
// bucketTot pre-zeroed by memset.
__global__ __launch_bounds__(512) void pAwt_kernel(
    const int* __restrict__ dst, int* __restrict__ bucketTot, int E,
    const float* __restrict__ W, const float* __restrict__ b,
    const float* __restrict__ gamma, const float* __restrict__ beta,
    const float* __restrict__ mean, const float* __restrict__ var,
    unsigned short* __restrict__ Wt, float* __restrict__ scv,
    float* __restrict__ pov, const float* __restrict__ x,
    unsigned short* __restrict__ xs, int total4) {
    __shared__ int lh[NBUCK];
    int tid = threadIdx.x;
    lh[tid] = 0;
    __syncthreads();
    for (int i = blockIdx.x * 512 + tid; i < E; i += gridDim.x * 512)
        atomicAdd(&lh[dst[i] >> BSHIFT], 1);
    // xs build (pure fp32->bf16 convert, deg-independent)
    const float4* x4 = (const float4*)x;
    ushort4* xs4 = (ushort4*)xs;
    for (int i = blockIdx.x * 512 + tid; i < total4; i += gridDim.x * 512) {
        float4 f = x4[i];
        ushort4 o;
        o.x = f2bf(f.x); o.y = f2bf(f.y);
        o.z = f2bf(f.z); o.w = f2bf(f.w);
        xs4[i] = o;
    }
    if (blockIdx.x < 16) {
        int t = blockIdx.x * 512 + tid;  // 0..8191
#pragma unroll
        for (int h = 0; h < 2; ++h) {
            int tt = t + h * 8192;
            Wt[(size_t)(tt & 127) * D + (tt >> 7)] = f2bf(W[tt]);
        }
        if (blockIdx.x == 0 && tid < D) {
            float sc = gamma[tid] * rsqrtf(var[tid] + BN_EPS);
            scv[tid] = sc;
            pov[tid] = (b[tid] - mean[tid]) * sc + beta[tid];
        }
    }
    __syncthreads();
    if (lh[tid]) atomicAdd(&bucketTot[tid], lh[tid]);
}

// ---------- pB: partition into bucket order (self-scanned bases) ----------
__global__ __launch_bounds__(512) void pB_kernel(const int* __restrict__ src,
                                                 const int* __restrict__ dst,
                                                 const int* __restrict__ bucketTot,
                                                 int* __restrict__ resCnt,
                                                 int2* __restrict__ pairs, int E) {
    __shared__ int sb[NBUCK];
    __shared__ int lh[NBUCK];
    __shared__ int lcur[NBUCK];
    int tid = threadIdx.x;
    sb[tid] = bucketTot[tid];
    lh[tid] = 0;
    __syncthreads();
    for (int d = 1; d < NBUCK; d <<= 1) {
        int v = (tid >= d) ? sb[tid - d] : 0;
        __syncthreads();
        sb[tid] += v;
        __syncthreads();
    }
    // sb = inclusive scan; exclusive base for bucket t = sb[t] - bucketTot[t]
    int chunk = (E + gridDim.x - 1) / gridDim.x;
    int base = blockIdx.x * chunk;
    int lim = min(chunk, E - base);
    if (lim <= 0) return;
    for (int i = tid; i < lim; i += 512) atomicAdd(&lh[dst[base + i] >> BSHIFT], 1);
    __syncthreads();
    int c = lh[tid];
    lcur[tid] = c ? (sb[tid] - bucketTot[tid]) + atomicAdd(&resCnt[tid], c) : 0;
    __syncthreads();
    for (int i = tid; i < lim; i += 512) {
        int s = src[base + i], d2 = dst[base + i];
        int pos = atomicAdd(&lcur[d2 >> BSHIFT], 1);
        pairs[pos] = make_int2(s, d2);
    }
}

// ---------- sort: within-bucket counting sort -> offs, colidx, dinv ----------
// One block per bucket (BNODES=256 nodes); slim (no x/xs work).
__global__ __launch_bounds__(512) void sort_kernel(
    const int2* __restrict__ pairs, const int* __restrict__ bucketTot,
    int* __restrict__ offs, int* __restrict__ colidx, float* __restrict__ dinv,
    int N, int E) {
    __shared__ int sb[NBUCK];
    __shared__ int lh[BNODES];
    __shared__ int lcur[BNODES];
    int tid = threadIdx.x;
    int b = blockIdx.x;
    sb[tid] = bucketTot[tid];
    __syncthreads();
    for (int d = 1; d < NBUCK; d <<= 1) {
        int v = (tid >= d) ? sb[tid - d] : 0;
        __syncthreads();
        sb[tid] += v;
        __syncthreads();
    }
    int cnt = bucketTot[b];
    int base = sb[b] - cnt;  // exclusive bucket base
    if (tid < BNODES) lh[tid] = 0;
    __syncthreads();
    for (int i = tid; i < cnt; i += 512)
        atomicAdd(&lh[pairs[base + i].y & (BNODES - 1)], 1);
    __syncthreads();
    int orig = (tid < BNODES) ? lh[tid] : 0;
    for (int d = 1; d < BNODES; d <<= 1) {
        int v = (tid < BNODES && tid >= d) ? lh[tid - d] : 0;
        __syncthreads();
        if (tid < BNODES) lh[tid] += v;
        __syncthreads();
    }
    if (tid < BNODES) {
        int exc = lh[tid] - orig;
        int node = b * BNODES + tid;
        if (node < N) {
            offs[node] = base + exc;
            dinv[node] = rsqrtf((float)(orig + 1));
        }
        lcur[tid] = exc;
    }
    if (b == 0 && tid == 0) offs[N] = E;
    __syncthreads();
    for (int i = tid; i < cnt; i += 512) {
        int2 p = pairs[base + i];
        int pos = atomicAdd(&lcur[p.y & (BNODES - 1)], 1);
        colidx[base + pos] = p.x;
    }
}

// ---------- fallback kernels (small-ws path) ----------
__global__ void deg_kernel(const int* __restrict__ dst, int* __restrict__ deg, int E) {
    int e = blockIdx.x * blockDim.x + threadIdx.x;
    if (e < E) atomicAdd(&deg[dst[e]], 1);
}

__global__ void dinv_kernel(const int* __restrict__ deg, float* __restrict__ dinv, int N) {
    int v = blockIdx.x * blockDim.x + threadIdx.x;
    if (v < N) dinv[v] = rsqrtf((float)(deg[v] + 1));
}

__global__ __launch_bounds__(256) void scan1_kernel(const int* __restrict__ deg,
                                                    int* __restrict__ bsum, int N) {
    __shared__ int s[256];
    int t = threadIdx.x;
    int v = blockIdx.x * 256 + t;
    s[t] = (v < N) ? deg[v] : 0;
    for (int st = 128; st > 0; st >>= 1) {
        __syncthreads();
        if (t < st) s[t] += s[t + st];
    }
    if (t == 0) bsum[blockIdx.x] = s[0];
}

__global__ __launch_bounds__(512) void scan2_kernel(int* __restrict__ bsum,
                                                    int* __restrict__ offs, int P, int N) {
    __shared__ int a[512];
    int t = threadIdx.x;
    int orig = (t < P) ? bsum[t] : 0;
    a[t] = orig;
    __syncthreads();
    for (int d = 1; d < 512; d <<= 1) {
        int tv = (t >= d) ? a[t - d] : 0;
        __syncthreads();
        a[t] += tv;
        __syncthreads();
    }
    if (t < P) bsum[t] = a[t] - orig;
    if (t == 0) offs[N] = a[511];
}

__global__ __launch_bounds__(256) void scan3_kernel(const int* __restrict__ deg,
                                                    const int* __restrict__ bsum,
                                                    int* __restrict__ offs,
                                                    int* __restrict__ cursor, int N) {
    __shared__ int a[256];
    int t = threadIdx.x;
    int v = blockIdx.x * 256 + t;
    int d = (v < N) ? deg[v] : 0;
    a[t] = d;
    __syncthreads();
    for (int st = 1; st < 256; st <<= 1) {
        int tv = (t >= st) ? a[t - st] : 0;
        __syncthreads();
        a[t] += tv;
        __syncthreads();
    }
    if (v < N) {
        int off = bsum[blockIdx.x] + a[t] - d;
        offs[v] = off;
        cursor[v] = off;
    }
}

__global__ void fill_kernel(const int* __restrict__ src, const int* __restrict__ dst,
                            int* __restrict__ cursor, int* __restrict__ colidx, int E) {
    int e = blockIdx.x * blockDim.x + threadIdx.x;
    if (e < E) {
        int d = dst[e];
        int pos = atomicAdd(&cursor[d], 1);
        colidx[pos] = src[e];
    }
}

// ---------- fallback aggregate (fp32, writes outp) ----------
__global__ __launch_bounds__(256) void agg_kernel(
    const float* __restrict__ x, const float* __restrict__ dinv,
    const int* __restrict__ offs, const int* __restrict__ colidx,
    float* __restrict__ outp, int N) {
    int wid = (blockIdx.x * blockDim.x + threadIdx.x) >> 6;
    if (wid >= N) return;
    int lane = threadIdx.x & 63;
    float dv = dinv[wid];
    int p = offs[wid], pe = offs[wid + 1];
    const float2* x2 = (const float2*)x;
    float2 s = x2[(size_t)wid * 64 + lane];
    float a0 = dv * s.x;
    float a1 = dv * s.y;
    for (; p < pe; ++p) {
        int u = colidx[p];
        float du = dinv[u];
        float2 vv = x2[(size_t)u * 64 + lane];
        a0 += du * vv.x;
        a1 += du * vv.y;
    }
    float2 r;
    r.x = dv * a0;
    r.y = dv * a1;
    ((float2*)outp)[(size_t)wid * 64 + lane] = r;
}

// ---------- fallback GEMM (reads fp32 outp in-place) ----------
__global__ __launch_bounds__(256) void gemm_kernel(
    float* __restrict__ outp, const float* __restrict__ xg,
    const unsigned short* __restrict__ Wt, const float* __restrict__ scv,
    const float* __restrict__ pov, int nTiles) {
    __shared__ uint4 sW4[2048];  // 32KB: [row][c4] swizzled c4^=(row&7)
    int tid = threadIdx.x;
    const uint4* W4 = (const uint4*)Wt;
#pragma unroll
    for (int i = 0; i < 8; ++i) {
        int q = tid + i * 256;
        int row = q >> 4, c4 = q & 15;
        sW4[row * 16 + (c4 ^ (row & 7))] = W4[q];
    }
    __syncthreads();

    int wid = (blockIdx.x * blockDim.x + tid) >> 6;
    if (wid >= nTiles) return;
    int lane = tid & 63;
    int m = lane & 15, quad = lane >> 4;
    int row0 = wid * 16;

    short8 A[4];
    const float* arow = outp + (size_t)(row0 + m) * D;
#pragma unroll
    for (int ks = 0; ks < 4; ++ks) {
        float4 f0 = *(const float4*)(arow + ks * 32 + quad * 8);
        float4 f1 = *(const float4*)(arow + ks * 32 + quad * 8 + 4);
        short8 af;
        af[0] = (short)f2bf(f0.x); af[1] = (short)f2bf(f0.y);
        af[2] = (short)f2bf(f0.z); af[3] = (short)f2bf(f0.w);
        af[4] = (short)f2bf(f1.x); af[5] = (short)f2bf(f1.y);
        af[6] = (short)f2bf(f1.z); af[7] = (short)f2bf(f1.w);
        A[ks] = af;
    }

#pragma unroll
    for (int cg = 0; cg < 8; ++cg) {
        int brow = cg * 16 + m;
        floatx4 acc = {0.f, 0.f, 0.f, 0.f};
#pragma unroll
        for (int ks = 0; ks < 4; ++ks) {
            short8 Bf = *(const short8*)&sW4[brow * 16 + ((ks * 4 + quad) ^ (m & 7))];
            acc = __builtin_amdgcn_mfma_f32_16x16x32_bf16(A[ks], Bf, acc, 0, 0, 0);
        }
        int col = cg * 16 + m;
        float sc = scv[col], po = pov[col];
#pragma unroll
        for (int i = 0; i < 4; ++i) {
            int row = row0 + quad * 4 + i;
            float bn = acc[i] * sc + po;
            size_t idx = (size_t)row * D + col;
            outp[idx] = fmaxf(bn, 0.f) + xg[idx];
        }
    }
}

// ---------- FUSED gather + MFMA GEMM + BN + ReLU + residual ----------
// Block = 16 nodes, 4 waves. Each wave gathers 4 nodes (full 64-lane row,
// a += dinv[u]*xs[u], predicated-16 batches), stages bf16 rows in padded LDS
// ([16][68] u32 -> 2-way conflicts only), then computes 2 column-groups of
// the 16x128 output tile with B-fragments from L2-resident Wt.
// Kills the aggb write+read (51.2MB) and one dispatch boundary.
__global__ __launch_bounds__(256) void aggemm_kernel(
    const unsigned short* __restrict__ xs, const float* __restrict__ dinv,
    const int* __restrict__ offs, const int* __restrict__ colidx,
    const float* __restrict__ xg, const unsigned short* __restrict__ Wt,
    const float* __restrict__ scv, const float* __restrict__ pov,
    float* __restrict__ outp, int N) {
    __shared__ unsigned int sA[16][68];  // padded: +4 dwords/row kills bank conflicts
    int tid = threadIdx.x;
    int lane = tid & 63;
    int w = tid >> 6;  // wave 0..3
    int row0 = blockIdx.x * 16;
    const unsigned int* xs32 = (const unsigned int*)xs;

    // ---- gather phase: wave w aggregates nodes row0 + w*4 .. +3 ----
#pragma unroll
    for (int k = 0; k < 4; ++k) {
        int nl = w * 4 + k;
        int node = row0 + nl;
        if (node < N) {
            float dv = dinv[node];
            unsigned int sv = xs32[(size_t)node * 64 + lane];
            float a0 = dv * bf2f((unsigned short)sv);
            float a1 = dv * bf2f((unsigned short)(sv >> 16));
            int p = offs[node], pe = offs[node + 1];
            for (; p + 16 <= pe; p += 16) {
                int u[16];
                float du[16];
                unsigned int v[16];
#pragma unroll
                for (int j = 0; j < 16; ++j) u[j] = colidx[p + j];
#pragma unroll
                for (int j = 0; j < 16; ++j) du[j] = dinv[u[j]];
#pragma unroll
                for (int j = 0; j < 16; ++j) v[j] = xs32[(size_t)u[j] * 64 + lane];
#pragma unroll
                for (int j = 0; j < 16; ++j) {
                    a0 = fmaf(du[j], bf2f((unsigned short)v[j]), a0);
                    a1 = fmaf(du[j], bf2f((unsigned short)(v[j] >> 16)), a1);
                }
            }
            int rem = pe - p;  // 0..15, uniform across the wave
            if (rem > 0) {
                int u[16];
                float du[16];
                unsigned int v[16];
#pragma unroll
                for (int j = 0; j < 16; ++j) u[j] = (j < rem) ? colidx[p + j] : 0;
#pragma unroll
                for (int j = 0; j < 16; ++j) du[j] = (j < rem) ? dinv[u[j]] : 0.f;
#pragma unroll
                for (int j = 0; j < 16; ++j)
                    v[j] = (j < rem) ? xs32[(size_t)u[j] * 64 + lane] : 0u;
#pragma unroll
                for (int j = 0; j < 16; ++j) {
                    a0 = fmaf(du[j], bf2f((unsigned short)v[j]), a0);
                    a1 = fmaf(du[j], bf2f((unsigned short)(v[j] >> 16)), a1);
                }
            }
            sA[nl][lane] = (unsigned int)f2bf(dv * a0) |
                           ((unsigned int)f2bf(dv * a1) << 16);
        } else {
            sA[nl][lane] = 0u;
        }
    }
    __syncthreads();

    // ---- GEMM phase: wave w computes cg = {2w, 2w+1} ----
    int m = lane & 15, quad = lane >> 4;
    short8 B[2][4];
#pragma unroll
    for (int c = 0; c < 2; ++c) {
        int brow = (w * 2 + c) * 16 + m;
#pragma unroll
        for (int ks = 0; ks < 4; ++ks)
            B[c][ks] = *(const short8*)&Wt[(size_t)brow * D + ks * 32 + quad * 8];
    }
    short8 A[4];
#pragma unroll
    for (int ks = 0; ks < 4; ++ks)
        A[ks] = *(const short8*)&sA[m][ks * 16 + quad * 4];

#pragma unroll
    for (int c = 0; c < 2; ++c) {
        floatx4 acc = {0.f, 0.f, 0.f, 0.f};
#pragma unroll
        for (int ks = 0; ks < 4; ++ks)
            acc = __builtin_amdgcn_mfma_f32_16x16x32_bf16(A[ks], B[c][ks], acc, 0, 0, 0);
        int col = (w * 2 + c) * 16 + m;
        float sc = scv[col], po = pov[col];
#pragma unroll
        for (int i = 0; i < 4; ++i) {
            int row = row0 + quad * 4 + i;
            if (row < N) {
                float bn = acc[i] * sc + po;
                size_t idx = (size_t)row * D + col;
                float xr = __builtin_nontemporal_load(xg + idx);
                __builtin_nontemporal_store(fmaxf(bn, 0.f) + xr, outp + idx);
            }
        }
    }
}

extern "C" void kernel_launch(void* const* d_in, const int* in_sizes, int n_in,
                              void* d_out, int out_size, void* d_ws, size_t ws_size,
                              hipStream_t stream) {
    const float* x = (const float*)d_in[0];
    const int* edge = (const int*)d_in[1];
    const float* Wm = (const float*)d_in[2];
    const float* b = (const float*)d_in[3];
    const float* gamma = (const float*)d_in[4];
    const float* beta = (const float*)d_in[5];
    const float* mean = (const float*)d_in[6];
    const float* var = (const float*)d_in[7];
    float* out = (float*)d_out;

    int N = in_sizes[0] / D;
    int E = in_sizes[1] / 2;
    const int* src = edge;
    const int* dst = edge + E;
    int P = (N + 255) / 256;

    // ---- workspace layout ----
    char* w = (char*)d_ws;
    size_t cur = 0;
    auto take = [&](size_t bytes) -> void* {
        cur = (cur + 15) & ~(size_t)15;
        void* p = w + cur;
        cur += bytes;
        return p;
    };
    int* deg = (int*)take((size_t)N * 4);
    int* bucketTot = (int*)take(NBUCK * 4);
    int* resCnt = (int*)take(NBUCK * 4);  // contiguous with bucketTot (one memset)
    float* dinv = (float*)take((size_t)N * 4);
    int* offs = (int*)take((size_t)(N + 1) * 4);
    int* cursor = (int*)take((size_t)N * 4);
    int* bsum = (int*)take((size_t)(P + 1) * 4);
    unsigned short* Wt = (unsigned short*)take((size_t)D * D * 2);
    float* scv = (float*)take(D * 4);
    float* pov = (float*)take(D * 4);
    int* colidx = (int*)take((size_t)E * 4);
    cur = (cur + 15) & ~(size_t)15;
    size_t fixedEnd = cur;

    size_t xsBytes = (size_t)N * D * 2;
    size_t zoneBytes = (xsBytes > (size_t)E * 8) ? xsBytes : (size_t)E * 8;
    bool fast = fixedEnd + xsBytes + zoneBytes <= ws_size;

    unsigned short* xs = nullptr;
    int2* pairs = nullptr;
    if (fast) {
        xs = (unsigned short*)(w + fixedEnd);
        pairs = (int2*)(w + fixedEnd + xsBytes);  // dead after sort_kernel
    }

    if (fast) {
        hipMemsetAsync(bucketTot, 0, (size_t)NBUCK * 8, stream);  // bucketTot+resCnt
        pAwt_kernel<<<1024, 512, 0, stream>>>(dst, bucketTot, E, Wm, b, gamma, beta,
                                              mean, var, Wt, scv, pov, x, xs, N * 32);
        pB_kernel<<<1024, 512, 0, stream>>>(src, dst, bucketTot, resCnt, pairs, E);
        sort_kernel<<<NBUCK, 512, 0, stream>>>(pairs, bucketTot, offs, colidx, dinv, N,
                                               E);
        aggemm_kernel<<<(N + 15) / 16, 256, 0, stream>>>(xs, dinv, offs, colidx, x, Wt,
                                                         scv, pov, out, N);
    } else {
        wt_kernel<<<(D * D) / 256, 256, 0, stream>>>(Wm, b, gamma, beta, mean, var, Wt,
                                                     scv, pov);
        hipMemsetAsync(deg, 0, sizeof(int) * N, stream);
        deg_kernel<<<(E + 255) / 256, 256, 0, stream>>>(dst, deg, E);
        dinv_kernel<<<(N + 255) / 256, 256, 0, stream>>>(deg, dinv, N);
        scan1_kernel<<<P, 256, 0, stream>>>(deg, bsum, N);
        scan2_kernel<<<1, 512, 0, stream>>>(bsum, offs, P, N);
        scan3_kernel<<<P, 256, 0, stream>>>(deg, bsum, offs, cursor, N);
        fill_kernel<<<(E + 255) / 256, 256, 0, stream>>>(src, dst, cursor, colidx, E);
        agg_kernel<<<(N * 64 + 255) / 256, 256, 0, stream>>>(x, dinv, offs, colidx, out,
                                                             N);
        int nTiles = (N + 15) / 16;
        gemm_kernel<<<(nTiles * 64 + 255) / 256, 256, 0, stream>>>(out, x, Wt, scv, pov,
                                                                   nTiles);
    }
}